// Round 15
// baseline (287.850 us; speedup 1.0000x reference)
//
#include <hip/hip_runtime.h>
#include <math.h>

// Problem: B=128, P=128, D=128, N=4096, fp32 in/out.
// probs = softmax(10*tanh((A@K)/sqrt(128)) + mask) over n.
//
// R15: fp16x3 MFMA GEMM with ds_read_b64_tr_b16 hardware-transpose operands.
//  K1: per block: C-tile 128p x 128n. K tile staged ONCE as 16dx16n subtiles
//      (hi/lo fp16), vectorized b64 writes (bank-uniform); B-fragments read
//      via tr_b16 (delivers d = 4g + j pattern = our A-side k-packing).
//      e = exp(10*tanh(score/sqrt(128)) + mask) -> O; row partials -> ws.
//      (max-free softmax: |10*tanh| <= 10 -> e <= 2.3e4, sum <= 9e7)
//  K2: O *= 1/rowsum (32 partials per row).
constexpr int BB = 128;
constexpr int PP = 128;
constexpr int DD = 128;
constexpr int NN = 4096;
constexpr float kC = 10.0f;
constexpr float k2InvSqrtD = 0.1767766952966369f;   // 2/sqrt(128)

constexpr int NTHR = 512;
constexpr int TEL = 272;             // tile stride in f16 elems (256 data + 16 pad = 544 B)

typedef float f32x4 __attribute__((ext_vector_type(4)));
typedef _Float16 f16x4 __attribute__((ext_vector_type(4)));
typedef _Float16 f16x8 __attribute__((ext_vector_type(8)));

__device__ __forceinline__ void st_nt_f4(float* p, float4 s) {
    f32x4 v = {s.x, s.y, s.z, s.w};
    __builtin_nontemporal_store(v, (f32x4*)p);
}

// Hardware transpose read: lane l (addr = base + 8l) receives elements
// (l&15) + 16j + 64*(l>>4) of the 256-elem (16d x 16n) tile at base, i.e.
// j=0..3 -> K[d_local = j + 4*(l>>4)][n_local = l&15].
__device__ __forceinline__ f16x4 tr_read(unsigned addr) {
    f16x4 r;
    asm volatile("ds_read_b64_tr_b16 %0, %1" : "=v"(r) : "v"(addr));
    return r;
}

// z = 10*tanh(s/sqrt(128)) + m, via tanh(x) = 1 - 2/(e^{2x}+1)
__device__ __forceinline__ float clip1(float s, float m) {
    const float e2 = __expf(s * k2InvSqrtD);
    const float r = __builtin_amdgcn_rcpf(e2 + 1.0f);
    return fmaf(-2.0f * kC, r, kC) + m;
}

// ===================== Kernel 1: staged GEMM + clip + exp =====================
// Grid: 4096 = 128 b x 32 n-tiles. 512 thr = 8 waves; wave w owns rows w*16..+15,
// all 128 cols. fp16x3: score = hh + hl + lh; k-packing
// d = kb*32 + 4g + (j&3) + 16*(j>>2) identical on A (regs) and B (tr reads).
// C/D layout (HW-verified): col = lane&15, row = 4*(lane>>4) + reg.
//
// LDS: 8x8 grid of 16dx16n tiles per array (hi, lo). Tile id = d_t*8 + n_t,
// elem = (d&15)*16 + (n&15), stride TEL (544 B) -> staging b64 writes are
// bank-uniform; tr reads consume 512 B contiguous per tile.
__global__ __launch_bounds__(NTHR, 2)
void score_kernel(const float* __restrict__ A,   // [B][P][D]
                  const float* __restrict__ K,   // [B][D][N]
                  const float* __restrict__ M,   // [B][P][N]
                  float* __restrict__ O,         // [B][P][N] <- exp(z)
                  float* __restrict__ ws) {      // [B*P][32] partial row sums
    __shared__ _Float16 Khi[64 * TEL];           // 34 KB
    __shared__ _Float16 Klo[64 * TEL];           // 34 KB

    const int l = blockIdx.x;
    const int b = l >> 5;
    const int ntb = l & 31;
    const int n_base = ntb * 128;

    const int tid = (int)threadIdx.x;
    const int lane = tid & 63;
    const int wid = tid >> 6;
    const int col = lane & 15;             // A row-in-frag / B col / C col
    const int g = lane >> 4;               // k-group / C row group
    const int kbase = 4 * g;

    // ---- Stage K tile [128 d][128 n] -> subtiled hi/lo LDS (once/block) ----
    const float* Kg = K + (size_t)b * DD * NN + n_base;
    {
        const int dl = tid >> 5;           // d & 15 (constant per thread)
        const int n4 = (tid & 31) * 4;     // 4 consecutive n
        const int tb = n4 >> 4;            // n-tile
        const int nin = n4 & 12;           // n within tile
        #pragma unroll
        for (int i = 0; i < 8; ++i) {      // d-tile = i
            const float4 v = *(const float4*)(Kg + (size_t)(16 * i + dl) * NN + n4);
            const float xs[4] = {v.x, v.y, v.z, v.w};
            f16x4 h, lo;
            #pragma unroll
            for (int e = 0; e < 4; ++e) {
                const _Float16 hh = (_Float16)xs[e];
                h[e] = hh;
                lo[e] = (_Float16)(xs[e] - (float)hh);
            }
            const int el = (i * 8 + tb) * TEL + dl * 16 + nin;
            *(f16x4*)&Khi[el] = h;         // ds_write_b64, bank-uniform
            *(f16x4*)&Klo[el] = lo;
        }
    }

    // ---- A fragments (regs, whole kernel): 16 rows x 128 d per wave ----
    const float* Arow = A + (size_t)(b * PP + wid * 16 + col) * DD;
    f16x8 ah[4], al[4];
    #pragma unroll
    for (int kb = 0; kb < 4; ++kb) {
        #pragma unroll
        for (int j = 0; j < 8; ++j) {
            const int d = kb * 32 + kbase + (j & 3) + 16 * (j >> 2);
            const float x = Arow[d];
            const _Float16 h = (_Float16)x;
            ah[kb][j] = h;
            al[kb][j] = (_Float16)(x - (float)h);
        }
    }
    __syncthreads();

    // per-lane LDS base addresses (low 32 bits of generic ptr = LDS offset)
    const unsigned khi0 = (unsigned)(uintptr_t)&Khi[0] + (unsigned)lane * 8u;
    const unsigned klo0 = (unsigned)(uintptr_t)&Klo[0] + (unsigned)lane * 8u;

    // ---- Main loop over 8 n-subtiles ----
    const size_t mrow0 = (size_t)(b * PP + wid * 16 + kbase) * NN + n_base + col;

    float rsum[4] = {0.f, 0.f, 0.f, 0.f};
    float mv[4];
    #pragma unroll
    for (int j = 0; j < 4; ++j) mv[j] = M[mrow0 + (size_t)j * NN];

    #pragma unroll 2
    for (int nt = 0; nt < 8; ++nt) {
        // prefetch next tile's mask early (HBM latency under MFMAs)
        float mvn[4] = {0.f, 0.f, 0.f, 0.f};
        if (nt < 7) {
            #pragma unroll
            for (int j = 0; j < 4; ++j)
                mvn[j] = M[mrow0 + (size_t)j * NN + (nt + 1) * 16];
        }

        // issue all 16 tr reads for this n-subtile
        f16x4 bh0[4], bh1[4], bl0[4], bl1[4];
        #pragma unroll
        for (int kb = 0; kb < 4; ++kb) {
            const unsigned t0 = (unsigned)(((2 * kb) * 8 + nt) * (TEL * 2));
            bh0[kb] = tr_read(khi0 + t0);
            bh1[kb] = tr_read(khi0 + t0 + 8u * (TEL * 2));   // next d-tile
            bl0[kb] = tr_read(klo0 + t0);
            bl1[kb] = tr_read(klo0 + t0 + 8u * (TEL * 2));
        }
        asm volatile("s_waitcnt lgkmcnt(0)" ::: "memory");
        __builtin_amdgcn_sched_barrier(0);   // rule #18: keep MFMAs below the wait

        f32x4 acc = {0.f, 0.f, 0.f, 0.f};
        #pragma unroll
        for (int kb = 0; kb < 4; ++kb) {
            const f16x8 bh = __builtin_shufflevector(bh0[kb], bh1[kb], 0, 1, 2, 3, 4, 5, 6, 7);
            const f16x8 bl = __builtin_shufflevector(bl0[kb], bl1[kb], 0, 1, 2, 3, 4, 5, 6, 7);
            acc = __builtin_amdgcn_mfma_f32_16x16x32_f16(ah[kb], bh, acc, 0, 0, 0);
            acc = __builtin_amdgcn_mfma_f32_16x16x32_f16(ah[kb], bl, acc, 0, 0, 0);
            acc = __builtin_amdgcn_mfma_f32_16x16x32_f16(al[kb], bh, acc, 0, 0, 0);
        }

        // epilogue: e = exp(clip + mask); store; row partials
        #pragma unroll
        for (int j = 0; j < 4; ++j) {
            const size_t off = mrow0 + (size_t)j * NN + nt * 16;
            const float e = __expf(clip1(acc[j], mv[j]));
            O[off] = e;                    // cached: K2 re-reads via L2/L3
            rsum[j] += e;
        }
        #pragma unroll
        for (int j = 0; j < 4; ++j) mv[j] = mvn[j];
    }

    // ---- reduce row partials across the 16 cols of each group -> ws ----
    #pragma unroll
    for (int j = 0; j < 4; ++j) {
        float s = rsum[j];
        s += __shfl_xor(s, 1);
        s += __shfl_xor(s, 2);
        s += __shfl_xor(s, 4);
        s += __shfl_xor(s, 8);
        rsum[j] = s;
    }
    if (col == 0) {
        #pragma unroll
        for (int j = 0; j < 4; ++j)
            ws[(size_t)(b * PP + wid * 16 + kbase + j) * 32 + ntb] = rsum[j];
    }
}

// ========================= Kernel 2: scale by 1/rowsum ========================
// Pure streaming: 2048 blocks x 256 thr; 32 threads/row, 32 f4/thread.
__global__ __launch_bounds__(256, 4)
void scale_kernel(float* __restrict__ O, const float* __restrict__ ws) {
    const int gtid = blockIdx.x * 256 + (int)threadIdx.x;
    const int row = gtid >> 5;
    const int seg = gtid & 31;

    const float* w = ws + (size_t)row * 32;
    float s = 0.f;
    #pragma unroll
    for (int i = 0; i < 8; ++i) {
        const float4 v = *(const float4*)(w + i * 4);
        s += (v.x + v.y) + (v.z + v.w);
    }
    const float inv = __builtin_amdgcn_rcpf(s);

    float4* R = (float4*)(O + (size_t)row * NN);
    #pragma unroll 8
    for (int i = 0; i < 32; ++i) {
        const int idx = i * 32 + seg;      // lanes consecutive -> coalesced
        float4 v = R[idx];
        v.x *= inv; v.y *= inv; v.z *= inv; v.w *= inv;
        st_nt_f4((float*)&R[idx], v);
    }
}

extern "C" void kernel_launch(void* const* d_in, const int* in_sizes, int n_in,
                              void* d_out, int out_size, void* d_ws, size_t ws_size,
                              hipStream_t stream) {
    const float* A = (const float*)d_in[0];   // mh_attn_out [128][128][128]
    const float* K = (const float*)d_in[1];   // single_head_key [128][128][4096]
    const float* M = (const float*)d_in[2];   // mask [128][128][4096]
    float* O = (float*)d_out;                 // probs [128][128][4096]
    float* ws = (float*)d_ws;                 // 16384 rows x 32 partials = 2 MB

    score_kernel<<<dim3(BB * 32), dim3(NTHR), 0, stream>>>(A, K, M, O, ws);
    scale_kernel<<<dim3(2048), dim3(256), 0, stream>>>(O, ws);
}